// Round 9
// baseline (8800.890 us; speedup 1.0000x reference)
//
#include <hip/hip_runtime.h>
#include <hip/hip_bf16.h>

typedef unsigned short ushort_t;
typedef unsigned int uint32;
typedef unsigned long long ull;
typedef short bf16x8 __attribute__((ext_vector_type(8)));
typedef float f32x4 __attribute__((ext_vector_type(4)));

#define Bb 64
#define Tt 512
#define Dd 512
#define Hh 1024
#define KK 1536
#define NBLK 64
#define OUT2_OFF 33554432ull
#define FLAGS_OFF 9699328ull
// flags: 64*32 u32 (8KB) + gen | flags2 (probe): +12288 B
#define XB_OFF    9728000ull
#define XB_BYTES  33554432ull

__device__ inline ushort_t f2b(float f) {
    __hip_bfloat16 h = __float2bfloat16(f);
    return __builtin_bit_cast(ushort_t, h);
}
__device__ inline float b2f(ushort_t u) {
    uint32 x = ((uint32)u) << 16;
    return __builtin_bit_cast(float, x);
}
__device__ inline bf16x8 ld_bf8(const ushort_t* p) {
    uint4 v = *reinterpret_cast<const uint4*>(p);
    return __builtin_bit_cast(bf16x8, v);
}
__device__ inline bf16x8 ld_x8(const float* p) {
    float4 u = *reinterpret_cast<const float4*>(p);
    float4 v = *reinterpret_cast<const float4*>(p + 4);
    bf16x8 a;
    a[0] = (short)f2b(u.x); a[1] = (short)f2b(u.y); a[2] = (short)f2b(u.z); a[3] = (short)f2b(u.w);
    a[4] = (short)f2b(v.x); a[5] = (short)f2b(v.y); a[6] = (short)f2b(v.z); a[7] = (short)f2b(v.w);
    return a;
}
// LLC-coherent 16B load (bypass L1/L2); caller drains vmcnt before use.
__device__ inline uint4 ld_c16(const ushort_t* p) {
    uint4 d;
    asm volatile("global_load_dwordx4 %0, %1, off sc0 sc1" : "=v"(d) : "v"(p) : "memory");
    return d;
}
__device__ inline bf16x8 as_bf(uint4 v) { return __builtin_bit_cast(bf16x8, v); }
__device__ inline void st_a8(ushort_t* p, ull v) {
    __hip_atomic_store((ull*)p, v, __ATOMIC_RELAXED, __HIP_MEMORY_SCOPE_AGENT);
}
__device__ inline uint32 ld_flag(const uint32* p) {
    return __hip_atomic_load(p, __ATOMIC_RELAXED, __HIP_MEMORY_SCOPE_AGENT);
}
__device__ inline float sigm(float x) { return 1.f / (1.f + __expf(-x)); }

#define MFMA(a, b, c) __builtin_amdgcn_mfma_f32_16x16x32_bf16((a), (b), (c), 0, 0, 0)

__global__ __launch_bounds__(256) void k_init(const float* __restrict__ state,
                                              ushort_t* __restrict__ HB, uint32* flags) {
    int i = blockIdx.x * 256 + threadIdx.x;
    if (i < Bb * Hh) HB[i] = f2b(state[i]);
    if (i < 6144) flags[i] = 0;   // clears flags + gen + flags2 probe array
}

__global__ __launch_bounds__(256) void k_xb(const float* __restrict__ inp,
                                            ushort_t* __restrict__ XB) {
    size_t i = ((size_t)blockIdx.x * 256 + threadIdx.x) * 8;
    bf16x8 v = ld_x8(inp + i);
    *reinterpret_cast<uint4*>(XB + i) = __builtin_bit_cast(uint4, v);
}

// WT[g][n][k] = bf16( k<512 ? Wx_g[k][n] : Wh_g[k-512][n] )
__global__ __launch_bounds__(256) void k_wt(const float* __restrict__ Wxz, const float* __restrict__ Whz,
                                            const float* __restrict__ Wxr, const float* __restrict__ Whr,
                                            const float* __restrict__ Wxh, const float* __restrict__ Whh,
                                            ushort_t* __restrict__ WT) {
    __shared__ float lds[64][65];
    int id = blockIdx.x;
    int g = id / 384, rem = id % 384, nt = rem / 24, kt = rem % 24;
    const float* Wx = (g == 0) ? Wxz : (g == 1) ? Wxr : Wxh;
    const float* Wh = (g == 0) ? Whz : (g == 1) ? Whr : Whh;
    int n0 = nt * 64, k0 = kt * 64;
    int tr = threadIdx.x >> 6, tc = threadIdx.x & 63;
    #pragma unroll
    for (int i = 0; i < 16; i++) {
        int kl = i * 4 + tr, k = k0 + kl;
        lds[kl][tc] = (k < 512) ? Wx[(size_t)k * Hh + n0 + tc]
                                : Wh[(size_t)(k - 512) * Hh + n0 + tc];
    }
    __syncthreads();
    #pragma unroll
    for (int i = 0; i < 16; i++) {
        int nl = i * 4 + tr;
        WT[((size_t)g * Hh + n0 + nl) * KK + k0 + tc] = f2b(lds[tc][nl]);
    }
}

// PROBE: pure flag barrier on flags2 — zero data movement. Measures protocol RTT only.
__device__ inline void dummy_barrier(uint32* flags2, uint32 val, int bi, int tid) {
    __syncthreads();
    if (tid == 0)
        __hip_atomic_store(flags2 + (uint32)bi * 32, val,
                           __ATOMIC_RELAXED, __HIP_MEMORY_SCOPE_AGENT);
    if (tid < 64) {
        uint32 vv = ld_flag(flags2 + tid * 32);
        while (__any((int)(vv < val))) {
            __builtin_amdgcn_s_sleep(1);
            vv = ld_flag(flags2 + tid * 32);
        }
    }
    __syncthreads();
}

// 4 waves; wave w owns m-tile w (batch rows w*16..+16), block owns cols bi*16..+16.
__global__ __launch_bounds__(256, 1) void gru_persist(
    const float* __restrict__ inp, const ushort_t* __restrict__ XB, int use_xb,
    const float* __restrict__ bz, const float* __restrict__ br, const float* __restrict__ bh,
    ushort_t* HB, ushort_t* RH, const ushort_t* __restrict__ WT,
    uint32* flags, float* __restrict__ out) {
    __shared__ ushort_t WL[3 * 48 * 512];   // 147456 B, slot-XOR-swizzled 1KB tiles
    __shared__ ushort_t STG[4 * 256];       // per-wave 16x16 store-coalescing tile

    const int bi = blockIdx.x;
    const int tid = threadIdx.x;
    uint32* flags2 = flags + 3072;          // probe array (own cache lines)

    // ---- prologue: stage weights into swizzled LDS tiles ----
    for (int idx = tid; idx < 9216; idx += 256) {     // 3g x 16col x 192 16B-chunks
        int g = idx / 3072, r = idx % 3072, col = r / 192, c8 = r % 192;
        int kc = c8 >> 2, slot = c8 & 3, ps = slot ^ ((col >> 1) & 3);
        const ushort_t* src = WT + ((size_t)g * Hh + bi * 16 + col) * KK + c8 * 8;
        *reinterpret_cast<uint4*>(WL + g * 24576 + kc * 512 + col * 32 + ps * 8) =
            *reinterpret_cast<const uint4*>(src);
    }

    const int l = tid & 63, w = tid >> 6;
    const int lrow = l & 15, lq = l >> 4;
    const int ncol = bi * 16 + lrow;
    const int wloff = lrow * 32 + (lq ^ ((lrow >> 1) & 3)) * 8;
    const int c0 = (bi + w) & 3;            // chunk stagger: per block AND per wave

    #define WTILE(g, kc) ld_bf8(WL + (g) * 24576 + (kc) * 512 + wloff)

    const int arow = w * 16 + lrow;
    const float*    xF = inp + (size_t)arow * (Tt * Dd) + lq * 8;
    const ushort_t* xBp = XB + (size_t)arow * (Tt * Dd) + lq * 8;
    const ushort_t* hb = HB + arow * Hh + lq * 8;
    const ushort_t* rb = RH + arow * Hh + lq * 8;
    const float bzv = bz[ncol], brv = br[ncol], bhv = bh[ncol];

    const size_t strow  = (size_t)(w * 16 + (l >> 2)) * Hh + bi * 16 + (l & 3) * 4;
    const int    stg_wr = w * 256;
    const int    stg_rd = w * 256 + (l >> 2) * 16 + (l & 3) * 4;

    float hold[4];
    #pragma unroll
    for (int j = 0; j < 4; j++)
        hold[j] = b2f(HB[(size_t)(w * 16 + lq * 4 + j) * Hh + ncol]);

    __syncthreads();

    const f32x4 z4 = {0.f, 0.f, 0.f, 0.f};
    f32x4 az = z4, ar = z4, ahx = z4;

    // x fragments + x-part MFMAs for t=0
    bf16x8 xa[16];
    if (use_xb) {
        #pragma unroll
        for (int i = 0; i < 16; i++) xa[i] = ld_bf8(xBp + i * 32);
    } else {
        #pragma unroll
        for (int i = 0; i < 16; i++) xa[i] = ld_x8(xF + i * 32);
    }
    #pragma unroll
    for (int kk = 0; kk < 16; kk++) {
        az  = MFMA(xa[kk], WTILE(0, kk), az);
        ar  = MFMA(xa[kk], WTILE(1, kk), ar);
        ahx = MFMA(xa[kk], WTILE(2, kk), ahx);
    }

    for (int t = 0; t < Tt; ++t) {
        const uint32 valH = 2u * (uint32)t;        // H(t) ready
        const uint32 valR = 2u * (uint32)t + 1u;   // RH(t) ready

        // ================= PHASE A: consume H(t) -> az, ar =================
        {
            uint32 v = ld_flag(flags + l * 32);    // one-shot fast check (not a loop)
            if (__all((int)(v >= valH))) {
                uint4 A[32];
                #pragma unroll
                for (int i = 0; i < 32; i++) A[i] = ld_c16(hb + i * 32);
                asm volatile("s_waitcnt vmcnt(0)" ::: "memory");
                __builtin_amdgcn_sched_barrier(0);
                #pragma unroll
                for (int kk = 0; kk < 32; kk++) {
                    az = MFMA(as_bf(A[kk]), WTILE(0, 16 + kk), az);
                    ar = MFMA(as_bf(A[kk]), WTILE(1, 16 + kk), ar);
                }
            } else {
                for (int ci = 0; ci < 4; ci++) {
                    int c = (c0 + ci) & 3;
                    uint32 vv = ld_flag(flags + (c * 16 + (l & 15)) * 32);
                    while (__any((int)(vv < valH))) {
                        __builtin_amdgcn_s_sleep(1);
                        vv = ld_flag(flags + (c * 16 + (l & 15)) * 32);
                    }
                    uint4 A[8];
                    #pragma unroll
                    for (int i = 0; i < 8; i++) A[i] = ld_c16(hb + (c * 8 + i) * 32);
                    asm volatile("s_waitcnt vmcnt(0)" ::: "memory");
                    __builtin_amdgcn_sched_barrier(0);
                    #pragma unroll
                    for (int i = 0; i < 8; i++) {
                        int kk = c * 8 + i;
                        az = MFMA(as_bf(A[i]), WTILE(0, 16 + kk), az);
                        ar = MFMA(as_bf(A[i]), WTILE(1, 16 + kk), ar);
                    }
                }
            }
        }
        // finalize z, r; stage + store RH slice
        float zreg[4];
        #pragma unroll
        for (int j = 0; j < 4; j++) {
            zreg[j] = sigm(az[j] + bzv);
            float rr = sigm(ar[j] + brv);
            STG[stg_wr + (lq * 4 + j) * 16 + lrow] = f2b(rr * hold[j]);
        }
        asm volatile("s_waitcnt lgkmcnt(0)" ::: "memory");
        st_a8(RH + strow, *reinterpret_cast<const ull*>(&STG[stg_rd]));
        asm volatile("s_waitcnt vmcnt(0)" ::: "memory");
        __syncthreads();
        if (tid == 0)
            __hip_atomic_store(flags + (uint32)bi * 32, valR,
                               __ATOMIC_RELAXED, __HIP_MEMORY_SCOPE_AGENT);

        // ====== PROBE: pure protocol barrier (no data) — measures RTT only ======
        dummy_barrier(flags2, valR, bi, tid);

        // cover RH propagation: issue x(t+1) fragment loads
        if (t < Tt - 1) {
            if (use_xb) {
                #pragma unroll
                for (int i = 0; i < 16; i++) xa[i] = ld_bf8(xBp + (size_t)(t + 1) * Dd + i * 32);
            } else {
                #pragma unroll
                for (int i = 0; i < 16; i++) xa[i] = ld_x8(xF + (size_t)(t + 1) * Dd + i * 32);
            }
        }

        // ================= PHASE B: consume RH(t) -> ah =================
        f32x4 ah0 = ahx, ah1 = z4;
        {
            uint32 v = ld_flag(flags + l * 32);
            if (__all((int)(v >= valR))) {
                uint4 A[32];
                #pragma unroll
                for (int i = 0; i < 32; i++) A[i] = ld_c16(rb + i * 32);
                asm volatile("s_waitcnt vmcnt(0)" ::: "memory");
                __builtin_amdgcn_sched_barrier(0);
                #pragma unroll
                for (int kk = 0; kk < 32; kk += 2) {
                    ah0 = MFMA(as_bf(A[kk]),     WTILE(2, 16 + kk),     ah0);
                    ah1 = MFMA(as_bf(A[kk + 1]), WTILE(2, 16 + kk + 1), ah1);
                }
            } else {
                for (int ci = 0; ci < 4; ci++) {
                    int c = (c0 + ci) & 3;
                    uint32 vv = ld_flag(flags + (c * 16 + (l & 15)) * 32);
                    while (__any((int)(vv < valR))) {
                        __builtin_amdgcn_s_sleep(1);
                        vv = ld_flag(flags + (c * 16 + (l & 15)) * 32);
                    }
                    uint4 A[8];
                    #pragma unroll
                    for (int i = 0; i < 8; i++) A[i] = ld_c16(rb + (c * 8 + i) * 32);
                    asm volatile("s_waitcnt vmcnt(0)" ::: "memory");
                    __builtin_amdgcn_sched_barrier(0);
                    #pragma unroll
                    for (int i = 0; i < 8; i++) {
                        int kk = c * 8 + i;
                        if (i & 1) ah1 = MFMA(as_bf(A[i]), WTILE(2, 16 + kk), ah1);
                        else       ah0 = MFMA(as_bf(A[i]), WTILE(2, 16 + kk), ah0);
                    }
                }
            }
        }
        f32x4 aht = ah0 + ah1;
        float hn[4];
        #pragma unroll
        for (int j = 0; j < 4; j++) {
            float pre = aht[j] + bhv;
            float e = __expf(-2.f * fabsf(pre));
            float th = (1.f - e) / (1.f + e);
            th = copysignf(th, pre);
            float v = zreg[j] * hold[j] + (1.f - zreg[j]) * th;
            hold[j] = v;
            hn[j] = v;
            STG[stg_wr + (lq * 4 + j) * 16 + lrow] = f2b(v);
        }
        asm volatile("s_waitcnt lgkmcnt(0)" ::: "memory");
        st_a8(HB + strow, *reinterpret_cast<const ull*>(&STG[stg_rd]));
        asm volatile("s_waitcnt vmcnt(0)" ::: "memory");
        __syncthreads();
        if (tid == 0)
            __hip_atomic_store(flags + (uint32)bi * 32, valR + 1u,
                               __ATOMIC_RELAXED, __HIP_MEMORY_SCOPE_AGENT);

        // ====== PROBE: second pure protocol barrier ======
        dummy_barrier(flags2, valR + 1u, bi, tid);

        // after the flag: out stores (consumed by nobody in-kernel)
        *reinterpret_cast<float4*>(out + (size_t)ncol * (Tt * Bb) + (size_t)t * Bb + w * 16 + lq * 4) =
            make_float4(hn[0], hn[1], hn[2], hn[3]);
        if (t == Tt - 1) {
            #pragma unroll
            for (int j = 0; j < 4; j++)
                out[OUT2_OFF + (size_t)(w * 16 + lq * 4 + j) * Hh + ncol] = hn[j];
        }

        // cover H(t+1) propagation: x(t+1) MFMAs
        az = z4; ar = z4; ahx = z4;
        if (t < Tt - 1) {
            #pragma unroll
            for (int kk = 0; kk < 16; kk++) {
                az  = MFMA(xa[kk], WTILE(0, kk), az);
                ar  = MFMA(xa[kk], WTILE(1, kk), ar);
                ahx = MFMA(xa[kk], WTILE(2, kk), ahx);
            }
        }
    }
    #undef WTILE
}

extern "C" void kernel_launch(void* const* d_in, const int* in_sizes, int n_in,
                              void* d_out, int out_size, void* d_ws, size_t ws_size,
                              hipStream_t stream) {
    const float* inp   = (const float*)d_in[0];
    const float* state = (const float*)d_in[1];
    const float* Wxz   = (const float*)d_in[2];
    const float* Whz   = (const float*)d_in[3];
    const float* bz    = (const float*)d_in[4];
    const float* Wxr   = (const float*)d_in[5];
    const float* Whr   = (const float*)d_in[6];
    const float* br    = (const float*)d_in[7];
    const float* Wxh   = (const float*)d_in[8];
    const float* Whh   = (const float*)d_in[9];
    const float* bh    = (const float*)d_in[10];
    float* out = (float*)d_out;

    char* ws = (char*)d_ws;
    ushort_t* HB    = (ushort_t*)(ws);
    ushort_t* RH    = (ushort_t*)(ws + 131072);
    ushort_t* WT    = (ushort_t*)(ws + 262144);
    uint32*   flags = (uint32*)(ws + FLAGS_OFF);
    ushort_t* XB    = (ushort_t*)(ws + XB_OFF);
    int use_xb = (ws_size >= XB_OFF + XB_BYTES) ? 1 : 0;

    k_init<<<dim3(256), dim3(256), 0, stream>>>(state, HB, flags);
    k_wt<<<dim3(1152), dim3(256), 0, stream>>>(Wxz, Whz, Wxr, Whr, Wxh, Whh, WT);
    if (use_xb)
        k_xb<<<dim3(8192), dim3(256), 0, stream>>>(inp, XB);

    void* args[] = {(void*)&inp, (void*)&XB, (void*)&use_xb,
                    (void*)&bz, (void*)&br, (void*)&bh,
                    (void*)&HB, (void*)&RH, (void*)&WT, (void*)&flags, (void*)&out};
    hipError_t e = hipLaunchCooperativeKernel((const void*)gru_persist, dim3(NBLK), dim3(256),
                                              args, 0, stream);
    if (e != hipSuccess) {
        gru_persist<<<dim3(NBLK), dim3(256), 0, stream>>>(inp, XB, use_xb, bz, br, bh,
                                                          HB, RH, WT, flags, out);
    }
}